// Round 9
// baseline (164.276 us; speedup 1.0000x reference)
//
#include <hip/hip_runtime.h>
#include <hip/hip_bf16.h>

// out[m,e] = sum_f relu( sum_q cos(x[m,q])cos(theta[q]) w1[f,q] ) * w2[e,f]
// M=16384, E=1024, F=4096. Pipeline:
//   1) w2cvt: w2 fp32 -> bf16 once into ws
//   2) qrelu: A = relu(qv @ w1^T) bf16 into ws
//   3) gemm: out = A @ w2bf^T -- 256x256 tile, BK=64, 8 waves (2m x 4n),
//      evenly-metered 8-phase schedule with ONE-PHASE READ-LOOKAHEAD:
//      every lgkm/vmcnt wait is counted and certifies only operations that
//      are >=1 full MFMA window old (wait ~ 0). LDS XOR-swizzle, XCD swizzle.

#define M_TOTAL 16384
#define E_DIM 1024
#define F_DIM 4096
#define NQ 8

typedef __attribute__((ext_vector_type(8))) short bf16x8;
typedef __attribute__((ext_vector_type(8))) unsigned short ushort8;
typedef __attribute__((ext_vector_type(4))) float f32x4;

__device__ __forceinline__ unsigned short f2bf(float f) {
  union { float f; unsigned u; } c; c.f = f;
  unsigned u = c.u + (0x7fffu + ((c.u >> 16) & 1u));
  return (unsigned short)(u >> 16);
}

// ---------------------------------------------------------------------------
__global__ __launch_bounds__(256) void w2cvt_kernel(
    const float* __restrict__ w2, unsigned short* __restrict__ w2bf) {
  size_t i = ((size_t)blockIdx.x * 256 + threadIdx.x) * 8;
  float v[8];
  *(float4*)&v[0] = *(const float4*)&w2[i];
  *(float4*)&v[4] = *(const float4*)&w2[i + 4];
  ushort8 p;
#pragma unroll
  for (int j = 0; j < 8; ++j) p[j] = f2bf(v[j]);
  *(ushort8*)&w2bf[i] = p;
}

// ---------------------------------------------------------------------------
__global__ __launch_bounds__(256) void qrelu_kernel(
    const float* __restrict__ x, const float* __restrict__ theta,
    const float* __restrict__ w1, unsigned short* __restrict__ A, int m_base) {
  __shared__ float qv[32][NQ];
  const int t = threadIdx.x;
  const int m0 = m_base + blockIdx.x * 32;
  {
    const int ml = t >> 3, q = t & 7;
    float xv = x[(size_t)(m0 + ml) * 1024 + q];
    qv[ml][q] = cosf(xv) * cosf(theta[q]);
  }
  __syncthreads();

  for (int oi = 0; oi < 2; ++oi) {
    const int o = t + oi * 256;  // f-octet index 0..511
    float w[64];
#pragma unroll
    for (int i = 0; i < 16; ++i)
      *(float4*)&w[i * 4] = *(const float4*)&w1[o * 64 + i * 4];
    for (int ml = 0; ml < 32; ++ml) {
      ushort8 pk;
#pragma unroll
      for (int j = 0; j < 8; ++j) {
        float s = 0.f;
#pragma unroll
        for (int q = 0; q < NQ; ++q) s = fmaf(qv[ml][q], w[j * 8 + q], s);
        pk[j] = f2bf(s > 0.f ? s : 0.f);
      }
      *(ushort8*)&A[(size_t)(m0 - m_base + ml) * F_DIM + o * 8] = pk;
    }
  }
}

// ---------------------------------------------------------------------------
// GEMM: BM=BN=256, BK=64, 512 thr = 8 waves (2m x 4n), wave tile 128x64.
// LDS: As/Bs [2 buf][2 half][128*64] bf16 = 128 KiB. Swizzle: (row, chunk c)
// at phys chunk c ^ (row&7); pre-swizzled DMA source, XOR'd ds_read.
// 8 phases per K-tile; phase = quadrant-half (ms,ns,kk), 8 MFMA each.
// Reads are issued ONE PHASE AHEAD (counted lgkm = #just-issued certifies
// exactly the current phase's operands, which are 1 MFMA-window old):
//   p0: st B(nb)h0     | rd BH0(b,k0)[2] | lgkm(2) | MFMA(AS0,BL0) q00 k0
//   p1: st B(nb)h1     | rd AS1(b,1,k0)[4]| lgkm(4)| MFMA(AS0,BH0) q01 k0
//   p2: st A(nb)h0     |                 | lgkm(0) | MFMA(AS1,BH0) q11 k0
//   p3: st A(nb)h1     | rd AS0+BL1 (k1)[6]| lgkm(6)| MFMA(AS1,BL0) q10 k0
//   p4:                | rd BH1(k1)[2]   | lgkm(2) | MFMA(AS0,BL1) q00 k1
//   p5:                | rd AS1(b,1,k1)[4]| lgkm(4)| MFMA(AS0,BH1) q01 k1
//   p6:                |                 | lgkm(0) | MFMA(AS1,BH1) q11 k1
//   p7: vmcnt(0)+BAR   | rd AS0+BL0 (nb,k0)[6]| lgkm(6)| MFMA(AS1,BL1) q10 k1
// vmcnt(0)@p7 is 4 phases (~2500 cyc) after the last DMA issue -> waits ~0.
// Reg-set WAR: every set rewritten >=2 phases after its last use.
// ---------------------------------------------------------------------------
#define BAR __builtin_amdgcn_s_barrier()
#define SB __builtin_amdgcn_sched_barrier(0)
#define VM0 asm volatile("s_waitcnt vmcnt(0)" ::: "memory")
#define LGKM(n) asm volatile("s_waitcnt lgkmcnt(" #n ")" ::: "memory")

#define GLDS(src, dst) \
  __builtin_amdgcn_global_load_lds( \
      (const __attribute__((address_space(1))) void*)(src), \
      (__attribute__((address_space(3))) void*)(dst), 16, 0, 0)

#define MFMA8(AS, BS, ms, ns) do { \
  __builtin_amdgcn_s_setprio(1); \
  _Pragma("unroll") \
  for (int j4 = 0; j4 < 4; ++j4) \
    _Pragma("unroll") \
    for (int j2 = 0; j2 < 2; ++j2) \
      acc[(ms) * 4 + j4][(ns) * 2 + j2] = \
          __builtin_amdgcn_mfma_f32_16x16x32_bf16( \
              AS[j4], BS[j2], acc[(ms) * 4 + j4][(ns) * 2 + j2], 0, 0, 0); \
  __builtin_amdgcn_s_setprio(0); \
  SB; \
} while (0)

#define RA(dst, b, ms, o) do { \
  _Pragma("unroll") \
  for (int j = 0; j < 4; ++j) \
    dst[j] = *(const bf16x8*)&asW[(b) * 16384 + ((ms) * 4 + j) * 1024 + (o)]; \
} while (0)

#define RB(dst, b, ns, o) do { \
  _Pragma("unroll") \
  for (int j = 0; j < 2; ++j) \
    dst[j] = *(const bf16x8*)&bsW[(b) * 16384 + ((ns) * 2 + j) * 1024 + (o)]; \
} while (0)

// One K-tile: b = buf, nb = b^1. LAST: skip staging and cross-tile reads.
#define TILE(b, nb, LAST) do { \
  /* p0 */ \
  if (!(LAST)) { GLDS(pB0, &Bs[nb][0][wid * 512]); pB0 += 64; \
                 GLDS(pB1, &Bs[nb][0][4096 + wid * 512]); pB1 += 64; } \
  BAR; RB(BH0, b, 1, bO0); LGKM(2); SB; MFMA8(AS0, BL0, 0, 0); BAR; \
  /* p1 */ \
  if (!(LAST)) { GLDS(pB2, &Bs[nb][1][wid * 512]); pB2 += 64; \
                 GLDS(pB3, &Bs[nb][1][4096 + wid * 512]); pB3 += 64; } \
  BAR; RA(AS1, b, 1, aO0); LGKM(4); SB; MFMA8(AS0, BH0, 0, 1); BAR; \
  /* p2 */ \
  if (!(LAST)) { GLDS(pA0, &As[nb][0][wid * 512]); pA0 += 64; \
                 GLDS(pA1, &As[nb][0][4096 + wid * 512]); pA1 += 64; } \
  BAR; LGKM(0); SB; MFMA8(AS1, BH0, 1, 1); BAR; \
  /* p3 */ \
  if (!(LAST)) { GLDS(pA2, &As[nb][1][wid * 512]); pA2 += 64; \
                 GLDS(pA3, &As[nb][1][4096 + wid * 512]); pA3 += 64; } \
  BAR; RA(AS0, b, 0, aO1); RB(BL1, b, 0, bO1); LGKM(6); SB; \
  MFMA8(AS1, BL0, 1, 0); BAR; \
  /* p4 */ \
  BAR; RB(BH1, b, 1, bO1); LGKM(2); SB; MFMA8(AS0, BL1, 0, 0); BAR; \
  /* p5 */ \
  BAR; RA(AS1, b, 1, aO1); LGKM(4); SB; MFMA8(AS0, BH1, 0, 1); BAR; \
  /* p6 */ \
  BAR; LGKM(0); SB; MFMA8(AS1, BH1, 1, 1); BAR; \
  /* p7 */ \
  VM0; BAR; \
  if (!(LAST)) { RA(AS0, nb, 0, aO0); RB(BL0, nb, 0, bO0); LGKM(6); } \
  else { LGKM(0); } \
  SB; MFMA8(AS1, BL1, 1, 0); BAR; \
} while (0)

__global__ __launch_bounds__(512, 2) void gemm_kernel(
    const unsigned short* __restrict__ Abf, const unsigned short* __restrict__ w2bf,
    float* __restrict__ out, int m_base) {
  __shared__ __align__(16) unsigned short As[2][2][128 * 64];
  __shared__ __align__(16) unsigned short Bs[2][2][128 * 64];

  const int tid = threadIdx.x;
  const int lane = tid & 63;
  const int wid = tid >> 6;
  const int wr = wid >> 2;  // m-half of block
  const int wc = wid & 3;   // n-quarter of block

  // T1: bijective XCD-chunked swizzle (m204); nb fastest within chunk so the
  // 4 blocks sharing an A-panel land on the same XCD (A L2-resident).
  const int nwg = gridDim.x;
  const int bid = blockIdx.x;
  const int qq = nwg >> 3, rr = nwg & 7;
  const int xcd = bid & 7, sub = bid >> 3;
  const int wgid =
      (xcd < rr ? xcd * (qq + 1) : rr * (qq + 1) + (xcd - rr) * qq) + sub;
  const int mb = wgid >> 2;
  const int nbk = wgid & 3;

  const unsigned short* Ag = Abf + (size_t)mb * 256 * F_DIM;
  const unsigned short* Bg = w2bf + (size_t)nbk * 256 * F_DIM;

  f32x4 acc[8][4] = {};
  bf16x8 AS0[4], AS1[4], BL0[2], BH0[2], BL1[2], BH1[2];

  // --- LDS read bases (fold to ds_read offset immediates) ---
  const int hi4 = lane >> 4, l7 = lane & 7, l15 = lane & 15;
  const int aO0 = l15 * 64 + ((hi4 ^ l7) << 3);
  const int aO1 = aO0 ^ 32;  // kk=1: chunk XOR 4
  const int bO0 = ((wc & 1) * 64 + l15) * 64 + ((hi4 ^ l7) << 3);
  const int bO1 = bO0 ^ 32;
  const unsigned short* asW = &As[0][wr][0];
  const unsigned short* bsW = &Bs[0][wc >> 1][0];

  // --- persistent global stage pointers (advance +64 elems per K-tile) ---
  const int srow = tid >> 3;              // 0..63
  const int sc = (tid & 7) ^ (srow & 7);  // source-side swizzle
  const unsigned short* pA0 = Ag + (size_t)(srow)*F_DIM + sc * 8;
  const unsigned short* pA1 = Ag + (size_t)(64 + srow) * F_DIM + sc * 8;
  const unsigned short* pA2 = Ag + (size_t)(128 + srow) * F_DIM + sc * 8;
  const unsigned short* pA3 = Ag + (size_t)(192 + srow) * F_DIM + sc * 8;
  const unsigned short* pB0 = Bg + (size_t)(srow)*F_DIM + sc * 8;
  const unsigned short* pB1 = Bg + (size_t)(64 + srow) * F_DIM + sc * 8;
  const unsigned short* pB2 = Bg + (size_t)(128 + srow) * F_DIM + sc * 8;
  const unsigned short* pB3 = Bg + (size_t)(192 + srow) * F_DIM + sc * 8;

  // --- prologue: stage kt0 -> buf0 fully; land; pre-read p0 operands ---
  GLDS(pB0, &Bs[0][0][wid * 512]); pB0 += 64;
  GLDS(pB1, &Bs[0][0][4096 + wid * 512]); pB1 += 64;
  GLDS(pB2, &Bs[0][1][wid * 512]); pB2 += 64;
  GLDS(pB3, &Bs[0][1][4096 + wid * 512]); pB3 += 64;
  GLDS(pA0, &As[0][0][wid * 512]); pA0 += 64;
  GLDS(pA1, &As[0][0][4096 + wid * 512]); pA1 += 64;
  GLDS(pA2, &As[0][1][wid * 512]); pA2 += 64;
  GLDS(pA3, &As[0][1][4096 + wid * 512]); pA3 += 64;
  VM0;
  BAR;
  RA(AS0, 0, 0, aO0);
  RB(BL0, 0, 0, bO0);

#pragma unroll 1
  for (int t2 = 0; t2 < 31; ++t2) {
    TILE(0, 1, 0);
    TILE(1, 0, 0);
  }
  TILE(0, 1, 0);
  TILE(1, 0, 1);

  // Epilogue: C/D layout col = lane&15, row = (lane>>4)*4 + r [m89-verified]
  const int cl = lane & 15, rg = lane >> 4;
  float* ob = out + (size_t)(m_base + mb * 256 + wr * 128) * E_DIM + nbk * 256 +
              wc * 64 + cl;
#pragma unroll
  for (int mt = 0; mt < 8; ++mt)
#pragma unroll
    for (int r = 0; r < 4; ++r) {
      float* orow = ob + (size_t)(mt * 16 + rg * 4 + r) * E_DIM;
#pragma unroll
      for (int nt = 0; nt < 4; ++nt) orow[nt * 16] = acc[mt][nt][r];
    }
}

// ---------------------------------------------------------------------------
extern "C" void kernel_launch(void* const* d_in, const int* in_sizes, int n_in,
                              void* d_out, int out_size, void* d_ws, size_t ws_size,
                              hipStream_t stream) {
  const float* x = (const float*)d_in[0];
  const float* theta = (const float*)d_in[1];
  const float* w1 = (const float*)d_in[2];
  const float* w2 = (const float*)d_in[3];
  float* out = (float*)d_out;

  unsigned short* w2bf = (unsigned short*)d_ws;           // 8 MiB
  unsigned short* A = w2bf + (size_t)E_DIM * F_DIM;       // rest of ws

  size_t abytes = ws_size - (size_t)E_DIM * F_DIM * 2;
  size_t maxrows = abytes / ((size_t)F_DIM * 2);
  int Mc = (int)((maxrows / 256) * 256);
  if (Mc > M_TOTAL) Mc = M_TOTAL;
  if (Mc < 256) Mc = 256;

  w2cvt_kernel<<<E_DIM * F_DIM / 2048, 256, 0, stream>>>(w2, w2bf);

  for (int mb = 0; mb < M_TOTAL; mb += Mc) {
    int rows = M_TOTAL - mb < Mc ? M_TOTAL - mb : Mc;
    qrelu_kernel<<<rows / 32, 256, 0, stream>>>(x, theta, w1, A, mb);
    gemm_kernel<<<(rows / 256) * 4, 512, 0, stream>>>(A, w2bf, out, mb);
  }
}